// Round 7
// baseline (295.801 us; speedup 1.0000x reference)
//
#include <hip/hip_runtime.h>

// Negative-ELBO fused reduction.
// total = sum_w [0.5*x^2 - 0.5*((x-mu)/sigma)^2 - ln(sigma)]
//       + (0.5/sp^2) * sum_b (y - mu_p)^2
//       + BATCH * (ln(sp) + HALF_LOG_2PI)
//
// R5: asm-volatile "+v" fence on ALL loaded vectors — compiler provably
// cannot sink loads past it (data dependency), so all 12/16 dwordx4 loads
// per thread are concurrently in flight with a single vmcnt drain.
// VGPR_Count >= ~72 is the verification that the fence held.

typedef float f32x4 __attribute__((ext_vector_type(4)));

constexpr int THREADS = 256;
constexpr int WITERS  = 4;   // float4 per thread, weights path (12 loads)
constexpr int PITERS  = 8;   // float4 per thread, pred path (16 loads)
constexpr float LN2          = 0.6931471805599453f;
constexpr float HALF_LOG_2PI = 0.9189385332046727f;

__device__ __forceinline__ float block_reduce(float v, float* lds4) {
    for (int off = 32; off > 0; off >>= 1)
        v += __shfl_down(v, off);
    int lane = threadIdx.x & 63;
    int wave = threadIdx.x >> 6;
    if (lane == 0) lds4[wave] = v;
    __syncthreads();
    return lds4[0] + lds4[1] + lds4[2] + lds4[3];
}

__global__ __launch_bounds__(THREADS, 4) void elbo_split(
    const float* __restrict__ xw,
    const float* __restrict__ muw,
    const float* __restrict__ sgw,
    const float* __restrict__ mup,
    const float* __restrict__ sp_ptr,
    const float* __restrict__ yt,
    float* __restrict__ partial,
    int wblocks)
{
    __shared__ float lds4[THREADS / 64];
    const int b = blockIdx.x;
    float v;

    if (b < wblocks) {
        // ---- weights term: 0.5*x^2 - 0.5*((x-mu)/sigma)^2 - ln(sigma) ----
        const f32x4* x4 = (const f32x4*)xw;
        const f32x4* m4 = (const f32x4*)muw;
        const f32x4* s4 = (const f32x4*)sgw;
        const int base = b * (THREADS * WITERS) + threadIdx.x;

        f32x4 xv[WITERS], mv[WITERS], sv[WITERS];
#pragma unroll
        for (int it = 0; it < WITERS; ++it) {
            int i = base + it * THREADS;
            xv[it] = x4[i];
            mv[it] = m4[i];
            sv[it] = s4[i];
        }
        // All 12 loads must complete before this point; all 48 data VGPRs live.
        asm volatile("" :
            "+v"(xv[0]), "+v"(xv[1]), "+v"(xv[2]), "+v"(xv[3]),
            "+v"(mv[0]), "+v"(mv[1]), "+v"(mv[2]), "+v"(mv[3]),
            "+v"(sv[0]), "+v"(sv[1]), "+v"(sv[2]), "+v"(sv[3]));

        float aw = 0.f;  // sum (x^2 - z^2)
        float al = 0.f;  // sum log2(sigma)
#pragma unroll
        for (int it = 0; it < WITERS; ++it) {
#pragma unroll
            for (int c = 0; c < 4; ++c) {
                float x  = xv[it][c];
                float dx = x - mv[it][c];
                float r  = __builtin_amdgcn_rcpf(sv[it][c]);
                float z  = dx * r;
                aw += x * x - z * z;
                al += __log2f(sv[it][c]);
            }
        }
        v = 0.5f * aw - LN2 * al;
    } else {
        // ---- likelihood term: (0.5/sp^2) * (y - mu_p)^2 ----
        const f32x4* p4 = (const f32x4*)mup;
        const f32x4* y4 = (const f32x4*)yt;
        const int base = (b - wblocks) * (THREADS * PITERS) + threadIdx.x;

        f32x4 pv[PITERS], yv[PITERS];
#pragma unroll
        for (int it = 0; it < PITERS; ++it) {
            int i = base + it * THREADS;
            pv[it] = p4[i];
            yv[it] = y4[i];
        }
        asm volatile("" :
            "+v"(pv[0]), "+v"(pv[1]), "+v"(pv[2]), "+v"(pv[3]),
            "+v"(pv[4]), "+v"(pv[5]), "+v"(pv[6]), "+v"(pv[7]),
            "+v"(yv[0]), "+v"(yv[1]), "+v"(yv[2]), "+v"(yv[3]),
            "+v"(yv[4]), "+v"(yv[5]), "+v"(yv[6]), "+v"(yv[7]));

        float ab = 0.f;
#pragma unroll
        for (int it = 0; it < PITERS; ++it) {
#pragma unroll
            for (int c = 0; c < 4; ++c) {
                float d = yv[it][c] - pv[it][c];
                ab += d * d;
            }
        }
        float sp = sp_ptr[0];
        v = 0.5f * __builtin_amdgcn_rcpf(sp * sp) * ab;
    }

    v = block_reduce(v, lds4);
    if (threadIdx.x == 0)
        partial[b] = v;
}

// Generic fallback (runtime sizes / non-divisible shapes).
__global__ __launch_bounds__(THREADS) void elbo_partial_generic(
    const float* __restrict__ xw,
    const float* __restrict__ muw,
    const float* __restrict__ sgw,
    const float* __restrict__ mup,
    const float* __restrict__ sp_ptr,
    const float* __restrict__ yt,
    float* __restrict__ partial,
    int n4w, int n4p)
{
    const float4* x4 = (const float4*)xw;
    const float4* m4 = (const float4*)muw;
    const float4* s4 = (const float4*)sgw;
    const float4* p4 = (const float4*)mup;
    const float4* y4 = (const float4*)yt;

    float aw = 0.f, al = 0.f, ab = 0.f;
    int idx    = blockIdx.x * blockDim.x + threadIdx.x;
    int stride = gridDim.x * blockDim.x;
    for (int i = idx; i < n4w; i += stride) {
        float4 xv = x4[i], mv = m4[i], sv = s4[i];
#define WCOMP(c) {                                  \
        float dx = xv.c - mv.c;                     \
        float r  = __builtin_amdgcn_rcpf(sv.c);     \
        float z  = dx * r;                          \
        aw += xv.c * xv.c - z * z;                  \
        al += __log2f(sv.c); }
        WCOMP(x) WCOMP(y) WCOMP(z) WCOMP(w)
#undef WCOMP
    }
    for (int i = idx; i < n4p; i += stride) {
        float4 pv = p4[i], yv = y4[i];
#define PCOMP(c) {                                  \
        float d = yv.c - pv.c;                      \
        ab += d * d; }
        PCOMP(x) PCOMP(y) PCOMP(z) PCOMP(w)
#undef PCOMP
    }
    float sp = sp_ptr[0];
    float v = 0.5f * aw - LN2 * al
            + 0.5f * __builtin_amdgcn_rcpf(sp * sp) * ab;

    __shared__ float lds4[THREADS / 64];
    v = block_reduce(v, lds4);
    if (threadIdx.x == 0)
        partial[blockIdx.x] = v;
}

__global__ __launch_bounds__(256) void elbo_final(
    const float* __restrict__ partial,
    const float* __restrict__ sp_ptr,
    float* __restrict__ out,
    int nblocks, float batch_f)
{
    float v = 0.f;
    for (int i = threadIdx.x; i < nblocks; i += 256)
        v += partial[i];
    for (int off = 32; off > 0; off >>= 1)
        v += __shfl_down(v, off);
    __shared__ float lds[4];
    int lane = threadIdx.x & 63;
    int wave = threadIdx.x >> 6;
    if (lane == 0) lds[wave] = v;
    __syncthreads();
    if (threadIdx.x == 0) {
        float sp = sp_ptr[0];
        float c  = batch_f * (logf(sp) + HALF_LOG_2PI);
        out[0] = lds[0] + lds[1] + lds[2] + lds[3] + c;
    }
}

extern "C" void kernel_launch(void* const* d_in, const int* in_sizes, int n_in,
                              void* d_out, int out_size, void* d_ws, size_t ws_size,
                              hipStream_t stream) {
    const float* xw  = (const float*)d_in[0];  // noisy_weights
    const float* muw = (const float*)d_in[1];  // mu_weights
    const float* sgw = (const float*)d_in[2];  // sigma_weights
    const float* mup = (const float*)d_in[3];  // mu_prediction
    const float* sp  = (const float*)d_in[4];  // sigma_prediction (scalar)
    const float* yt  = (const float*)d_in[5];  // y_true
    float* out     = (float*)d_out;
    float* partial = (float*)d_ws;

    int nw  = in_sizes[0];          // N_WEIGHTS
    int np  = in_sizes[5];          // BATCH
    int n4w = nw / 4;
    int n4p = np / 4;
    const int wchunk = THREADS * WITERS;
    const int pchunk = THREADS * PITERS;

    if ((nw % 4 == 0) && (np % 4 == 0) &&
        (n4w % wchunk == 0) && (n4p % pchunk == 0)) {
        int wblocks = n4w / wchunk;        // 4096 for 2^24
        int pblocks = n4p / pchunk;        // 2048 for 2^24
        int nblocks = wblocks + pblocks;
        elbo_split<<<nblocks, THREADS, 0, stream>>>(
            xw, muw, sgw, mup, sp, yt, partial, wblocks);
        elbo_final<<<1, 256, 0, stream>>>(partial, sp, out, nblocks,
                                          (float)np);
    } else {
        int nblocks = 2048;
        elbo_partial_generic<<<nblocks, THREADS, 0, stream>>>(
            xw, muw, sgw, mup, sp, yt, partial, n4w, n4p);
        elbo_final<<<1, 256, 0, stream>>>(partial, sp, out, nblocks,
                                          (float)np);
    }
}

// Round 8
// 266.207 us; speedup vs baseline: 1.1112x; 1.1112x over previous
//
#include <hip/hip_runtime.h>
#include <stdint.h>

// Negative-ELBO fused reduction.
// total = 0.5*sum(x^2 - ((x-mu)/sig)^2) - sum(ln sig)
//       + (0.5/sp^2)*sum((y-mu_p)^2) + BATCH*(ln sp + HALF_LOG_2PI)
//
// R7: loads are volatile inline-asm global_load_dwordx4 with nt flag.
//  - volatile asm order is architecturally fixed -> 12/16 loads issue
//    back-to-back, ONE s_waitcnt vmcnt(0) drain (true MLP, theory A).
//  - nt: reads don't allocate in L2/L3 -> no dirty-line evictions of the
//    harness restore data -> kills the 193MB concurrent writeback (theory E).
// Verification bits: VGPR_Count >= ~70, WRITE_SIZE << 193MB.

typedef float f32x4 __attribute__((ext_vector_type(4)));

constexpr int THREADS = 256;
constexpr int WITERS  = 4;   // 12 loads in flight, weights path
constexpr int PITERS  = 8;   // 16 loads in flight, pred path
constexpr float LN2          = 0.6931471805599453f;
constexpr float HALF_LOG_2PI = 0.9189385332046727f;

#define GLOAD_NT(dst, voff, sbase)                                  \
    asm volatile("global_load_dwordx4 %0, %1, %2 nt"                \
                 : "=v"(dst) : "v"(voff), "s"(sbase))

__device__ __forceinline__ float block_reduce(float v, float* lds4) {
    for (int off = 32; off > 0; off >>= 1)
        v += __shfl_down(v, off);
    int lane = threadIdx.x & 63;
    int wave = threadIdx.x >> 6;
    if (lane == 0) lds4[wave] = v;
    __syncthreads();
    return lds4[0] + lds4[1] + lds4[2] + lds4[3];
}

__global__ __launch_bounds__(THREADS, 4) void elbo_split(
    const float* __restrict__ xw,
    const float* __restrict__ muw,
    const float* __restrict__ sgw,
    const float* __restrict__ mup,
    const float* __restrict__ sp_ptr,
    const float* __restrict__ yt,
    float* __restrict__ partial,
    int wblocks)
{
    __shared__ float lds4[THREADS / 64];
    const int b = blockIdx.x;
    float v;

    if (b < wblocks) {
        // ---- weights term: 0.5*x^2 - 0.5*((x-mu)/sig)^2 - ln(sig) ----
        const size_t boff = (size_t)b * (THREADS * WITERS * 4);
        const float* bx = xw  + boff;
        const float* bm = muw + boff;
        const float* bs = sgw + boff;
        const uint32_t off0 = threadIdx.x * 16u;

        f32x4 xv[WITERS], mv[WITERS], sv[WITERS];
#pragma unroll
        for (int it = 0; it < WITERS; ++it) {
            uint32_t off = off0 + (uint32_t)(it * 4096);
            GLOAD_NT(xv[it], off, bx);
            GLOAD_NT(mv[it], off, bm);
            GLOAD_NT(sv[it], off, bs);
        }
        asm volatile("s_waitcnt vmcnt(0)" ::: "memory");
        __builtin_amdgcn_sched_barrier(0);

        float aw = 0.f;  // sum (x^2 - z^2)
        float al = 0.f;  // sum log2(sigma)
#pragma unroll
        for (int it = 0; it < WITERS; ++it) {
#pragma unroll
            for (int c = 0; c < 4; ++c) {
                float x  = xv[it][c];
                float dx = x - mv[it][c];
                float r  = __builtin_amdgcn_rcpf(sv[it][c]);
                float z  = dx * r;
                aw += x * x - z * z;
                al += __log2f(sv[it][c]);
            }
        }
        v = 0.5f * aw - LN2 * al;
    } else {
        // ---- likelihood term: (0.5/sp^2) * (y - mu_p)^2 ----
        const size_t boff = (size_t)(b - wblocks) * (THREADS * PITERS * 4);
        const float* bp = mup + boff;
        const float* by = yt  + boff;
        const uint32_t off0 = threadIdx.x * 16u;

        f32x4 pv[PITERS], yv[PITERS];
#pragma unroll
        for (int it = 0; it < PITERS; ++it) {
            uint32_t off = off0 + (uint32_t)(it * 4096);
            GLOAD_NT(pv[it], off, bp);
            GLOAD_NT(yv[it], off, by);
        }
        asm volatile("s_waitcnt vmcnt(0)" ::: "memory");
        __builtin_amdgcn_sched_barrier(0);

        float ab = 0.f;
#pragma unroll
        for (int it = 0; it < PITERS; ++it) {
#pragma unroll
            for (int c = 0; c < 4; ++c) {
                float d = yv[it][c] - pv[it][c];
                ab += d * d;
            }
        }
        float sp = sp_ptr[0];
        v = 0.5f * __builtin_amdgcn_rcpf(sp * sp) * ab;
    }

    v = block_reduce(v, lds4);
    if (threadIdx.x == 0)
        partial[b] = v;
}

// Generic fallback (runtime sizes / non-divisible shapes).
__global__ __launch_bounds__(THREADS) void elbo_partial_generic(
    const float* __restrict__ xw,
    const float* __restrict__ muw,
    const float* __restrict__ sgw,
    const float* __restrict__ mup,
    const float* __restrict__ sp_ptr,
    const float* __restrict__ yt,
    float* __restrict__ partial,
    int n4w, int n4p)
{
    const float4* x4 = (const float4*)xw;
    const float4* m4 = (const float4*)muw;
    const float4* s4 = (const float4*)sgw;
    const float4* p4 = (const float4*)mup;
    const float4* y4 = (const float4*)yt;

    float aw = 0.f, al = 0.f, ab = 0.f;
    int idx    = blockIdx.x * blockDim.x + threadIdx.x;
    int stride = gridDim.x * blockDim.x;
    for (int i = idx; i < n4w; i += stride) {
        float4 xv = x4[i], mv = m4[i], sv = s4[i];
#define WCOMP(c) {                                  \
        float dx = xv.c - mv.c;                     \
        float r  = __builtin_amdgcn_rcpf(sv.c);     \
        float z  = dx * r;                          \
        aw += xv.c * xv.c - z * z;                  \
        al += __log2f(sv.c); }
        WCOMP(x) WCOMP(y) WCOMP(z) WCOMP(w)
#undef WCOMP
    }
    for (int i = idx; i < n4p; i += stride) {
        float4 pv = p4[i], yv = y4[i];
#define PCOMP(c) {                                  \
        float d = yv.c - pv.c;                      \
        ab += d * d; }
        PCOMP(x) PCOMP(y) PCOMP(z) PCOMP(w)
#undef PCOMP
    }
    float sp = sp_ptr[0];
    float v = 0.5f * aw - LN2 * al
            + 0.5f * __builtin_amdgcn_rcpf(sp * sp) * ab;

    __shared__ float lds4[THREADS / 64];
    v = block_reduce(v, lds4);
    if (threadIdx.x == 0)
        partial[blockIdx.x] = v;
}

__global__ __launch_bounds__(256) void elbo_final(
    const float* __restrict__ partial,
    const float* __restrict__ sp_ptr,
    float* __restrict__ out,
    int nblocks, float batch_f)
{
    float v = 0.f;
    for (int i = threadIdx.x; i < nblocks; i += 256)
        v += partial[i];
    for (int off = 32; off > 0; off >>= 1)
        v += __shfl_down(v, off);
    __shared__ float lds[4];
    int lane = threadIdx.x & 63;
    int wave = threadIdx.x >> 6;
    if (lane == 0) lds[wave] = v;
    __syncthreads();
    if (threadIdx.x == 0) {
        float sp = sp_ptr[0];
        float c  = batch_f * (logf(sp) + HALF_LOG_2PI);
        out[0] = lds[0] + lds[1] + lds[2] + lds[3] + c;
    }
}

extern "C" void kernel_launch(void* const* d_in, const int* in_sizes, int n_in,
                              void* d_out, int out_size, void* d_ws, size_t ws_size,
                              hipStream_t stream) {
    const float* xw  = (const float*)d_in[0];  // noisy_weights
    const float* muw = (const float*)d_in[1];  // mu_weights
    const float* sgw = (const float*)d_in[2];  // sigma_weights
    const float* mup = (const float*)d_in[3];  // mu_prediction
    const float* sp  = (const float*)d_in[4];  // sigma_prediction (scalar)
    const float* yt  = (const float*)d_in[5];  // y_true
    float* out     = (float*)d_out;
    float* partial = (float*)d_ws;

    int nw  = in_sizes[0];          // N_WEIGHTS
    int np  = in_sizes[5];          // BATCH
    int n4w = nw / 4;
    int n4p = np / 4;
    const int wchunk = THREADS * WITERS;
    const int pchunk = THREADS * PITERS;

    if ((nw % 4 == 0) && (np % 4 == 0) &&
        (n4w % wchunk == 0) && (n4p % pchunk == 0)) {
        int wblocks = n4w / wchunk;        // 4096 for 2^24
        int pblocks = n4p / pchunk;        // 2048 for 2^24
        int nblocks = wblocks + pblocks;
        elbo_split<<<nblocks, THREADS, 0, stream>>>(
            xw, muw, sgw, mup, sp, yt, partial, wblocks);
        elbo_final<<<1, 256, 0, stream>>>(partial, sp, out, nblocks,
                                          (float)np);
    } else {
        int nblocks = 2048;
        elbo_partial_generic<<<nblocks, THREADS, 0, stream>>>(
            xw, muw, sgw, mup, sp, yt, partial, n4w, n4p);
        elbo_final<<<1, 256, 0, stream>>>(partial, sp, out, nblocks,
                                          (float)np);
    }
}